// Round 9
// baseline (555.226 us; speedup 1.0000x reference)
//
#include <hip/hip_runtime.h>
#include <math.h>

constexpr int B_ = 32, T_ = 512, N_ = 7, BN_ = 224;
constexpr int L_ = 64, DM_ = 32, PLEN_ = 16;
constexpr int HF_ = 256, NH_ = 8, DFF_ = 32;
constexpr int S_ = 1000, SP_ = 1024, DLLM_ = 4096, V_ = 32000;
constexpr int PRED_ = 96, HNF_ = 2048;
constexpr int KSPLIT2 = 25, KCH2 = 1280;  // GEMM2 split-K: 25 * 1280 = 32000

typedef short bf16x8 __attribute__((ext_vector_type(8)));
typedef float f32x4 __attribute__((ext_vector_type(4)));

__device__ inline ushort f2bf(float x) {
    union { float f; uint u; } v; v.f = x;
    uint r = v.u + 0x7fffu + ((v.u >> 16) & 1u);  // RNE
    return (ushort)(r >> 16);
}
__device__ inline uint pk(float a, float b) {
    return (uint)f2bf(a) | ((uint)f2bf(b) << 16);
}
__device__ inline void gl16(const void* g, void* l) {
    __builtin_amdgcn_global_load_lds(
        (const __attribute__((address_space(1))) void*)g,
        (__attribute__((address_space(3))) void*)l, 16, 0, 0);
}

// ---------------- fused: stats + normalize + conv embed + q-projection ----------------
__global__ __launch_bounds__(256) void k_pre(const float* __restrict__ x,
                                             const float* __restrict__ conv_w,
                                             const float* __restrict__ wq,
                                             const float* __restrict__ bq,
                                             float* __restrict__ mean_o,
                                             float* __restrict__ std_o,
                                             float* __restrict__ qo) {
    const int bn = blockIdx.x, b = bn / N_, n = bn % N_;
    __shared__ float xn[520];
    __shared__ float cw[DM_ * PLEN_ * 3];
    __shared__ float enc_s[2048];
    __shared__ float wqs[HF_ * DM_];
    __shared__ float rs[4], rq[4], sm2[2];
    const int tid = threadIdx.x;
    const float* xp = x + (size_t)b * T_ * N_ + n;

    // stats + concurrent weight staging
    float s = 0.f, sq = 0.f;
    for (int t = tid; t < T_; t += 256) { float v = xp[(size_t)t * N_]; s += v; sq += v * v; }
    for (int i = tid; i < DM_ * PLEN_ * 3; i += 256) cw[i] = conv_w[i];
    for (int i = tid; i < HF_ * DM_; i += 256) wqs[i] = wq[i];
    for (int o = 32; o > 0; o >>= 1) { s += __shfl_down(s, o, 64); sq += __shfl_down(sq, o, 64); }
    int wid = tid >> 6, lane = tid & 63;
    if (lane == 0) { rs[wid] = s; rq[wid] = sq; }
    __syncthreads();
    if (tid == 0) {
        float S = rs[0] + rs[1] + rs[2] + rs[3];
        float Q = rq[0] + rq[1] + rq[2] + rq[3];
        float m = S / T_;
        float var = Q / T_ - m * m;
        float sd = sqrtf(var + 1e-5f);
        mean_o[bn] = m; std_o[bn] = sd;
        sm2[0] = m; sm2[1] = sd;
    }
    __syncthreads();
    const float m = sm2[0], rstd = 1.0f / sm2[1];
    for (int t = tid; t < T_; t += 256) xn[t] = (xp[(size_t)t * N_] - m) * rstd;
    __syncthreads();
    if (tid < 8) xn[T_ + tid] = xn[T_ - 1];
    __syncthreads();
    // conv embed -> enc_s (LDS)
    for (int idx = tid; idx < L_ * DM_ * 8; idx += 256) { }  // (no-op guard removed)
    for (int idx = tid; idx < L_ * DM_; idx += 256) {
        int l = idx >> 5, o = idx & 31;
        float acc = 0.f;
        #pragma unroll
        for (int t = 0; t < 3; t++) {
            int col = l + t;
            int pcol = (col == 0) ? 63 : ((col == 65) ? 0 : col - 1);
            const float* xb = &xn[pcol * 8];
            const float* cwb = &cw[o * 48 + t];
            #pragma unroll
            for (int i = 0; i < 16; i++) acc += xb[i] * cwb[i * 3];
        }
        enc_s[idx] = acc;
    }
    __syncthreads();
    // q projection
    const float scale = 0.17677669529663687f;  // 1/sqrt(32)
    for (int idx = tid; idx < L_ * HF_; idx += 256) {
        int l = idx >> 8, c = idx & 255;
        float acc = bq[c];
        const float* e = &enc_s[l * 32];
        const float* w = &wqs[c * 32];
        #pragma unroll
        for (int k = 0; k < 32; k++) acc += e[k] * w[k];
        qo[(size_t)bn * L_ * HF_ + idx] = acc * scale;
    }
}

// ---------------- wsum[c] = sum_d wkv[c][d] (exact f32, for map_b folding) ----------------
__global__ __launch_bounds__(256) void k_wsum(const float* __restrict__ wk,
                                              const float* __restrict__ wv,
                                              float* __restrict__ wsum) {
    int c = blockIdx.x;
    const float* row = (c < HF_) ? wk + (size_t)c * DLLM_ : wv + (size_t)(c - HF_) * DLLM_;
    float s = 0.f;
    for (int d = threadIdx.x; d < DLLM_; d += 256) s += row[d];
    for (int o = 32; o > 0; o >>= 1) s += __shfl_down(s, o, 64);
    __shared__ float rs[4];
    int wid = threadIdx.x >> 6, lane = threadIdx.x & 63;
    if (lane == 0) rs[wid] = s;
    __syncthreads();
    if (threadIdx.x == 0) wsum[c] = rs[0] + rs[1] + rs[2] + rs[3];
}

// ---------------- cvt wk,wv -> wkv_bf [512][4096] bf16 ----------------
__global__ __launch_bounds__(256) void k_cvt_wkv(const float* __restrict__ wk,
                                                 const float* __restrict__ wv,
                                                 ushort* __restrict__ out) {
    int g = blockIdx.x * 256 + threadIdx.x;
    int e = g * 8;
    const float* src = (e < HF_ * DLLM_) ? wk + e : wv + (e - HF_ * DLLM_);
    float4 x = *(const float4*)src, y = *(const float4*)(src + 4);
    uint4 w; w.x = pk(x.x, x.y); w.y = pk(x.z, x.w); w.z = pk(y.x, y.y); w.w = pk(y.z, y.w);
    *(uint4*)(out + e) = w;
}

// ---------------- GEMM1 (bf16 MFMA, counted-vmcnt pipeline) ----------------
// E_T[512][32000] = (word_emb @ wkv^T)^T. BM=128, BN=256, BK=32, 512 thr (8 waves 2x4).
__global__ __launch_bounds__(512) void k_gemm1(const float* __restrict__ A,
                                               const ushort* __restrict__ Bw,
                                               ushort* __restrict__ ET) {
    __shared__ union {
        struct { float Af[2][128 * 32]; ushort Bs[2][256 * 32]; } st;  // 64 KB
        ushort C[256 * 72];                                            // 36 KB epilogue
    } lds;
    const int tid = threadIdx.x;
    const int lane = tid & 63, wid = tid >> 6;
    const int wr = wid >> 2, wc = wid & 3;
    const int n0 = blockIdx.x * 256, m0 = blockIdx.y * 128;

    const int arw = tid >> 3, acq = (tid & 7) ^ ((tid >> 3) & 7);
    const float* asrc0 = A + (size_t)(m0 + arw) * DLLM_ + acq * 4;
    const float* asrc1 = asrc0 + (size_t)64 * DLLM_;

    const int u0 = tid, rb0 = u0 >> 2, ob0 = (u0 & 3) ^ ((rb0 >> 1) & 3);
    const int u1 = tid + 512, rb1 = u1 >> 2, ob1 = (u1 & 3) ^ ((rb1 >> 1) & 3);
    const ushort* bptr0 = Bw + (size_t)(n0 + rb0) * DLLM_ + ob0 * 8;
    const ushort* bptr1 = Bw + (size_t)(n0 + rb1) * DLLM_ + ob1 * 8;

    const int rl = lane & 15, g = lane >> 4;
    const int oc = g ^ ((rl >> 1) & 3);

    f32x4 acc[4][4];
    #pragma unroll
    for (int i = 0; i < 4; i++)
        #pragma unroll
        for (int j = 0; j < 4; j++) acc[i][j] = (f32x4){0.f, 0.f, 0.f, 0.f};

    gl16(asrc0, &lds.st.Af[0][tid * 4]);
    gl16(asrc1, &lds.st.Af[0][(tid + 512) * 4]);
    gl16(bptr0, &lds.st.Bs[0][u0 * 8]);
    gl16(bptr1, &lds.st.Bs[0][u1 * 8]);
    __syncthreads();

    int cur = 0;
    constexpr int NT = DLLM_ / 32;  // 128
    for (int t = 0; t < NT; ++t) {
        if (t + 1 < NT) {
            const int o = (t + 1) * 32;
            gl16(asrc0 + o, &lds.st.Af[cur ^ 1][tid * 4]);
            gl16(asrc1 + o, &lds.st.Af[cur ^ 1][(tid + 512) * 4]);
            gl16(bptr0 + o, &lds.st.Bs[cur ^ 1][u0 * 8]);
            gl16(bptr1 + o, &lds.st.Bs[cur ^ 1][u1 * 8]);
            asm volatile("s_waitcnt vmcnt(4)" ::: "memory");
        } else {
            asm volatile("s_waitcnt vmcnt(0)" ::: "memory");
        }
        __builtin_amdgcn_s_barrier();
        asm volatile("" ::: "memory");
        const float* Ab = lds.st.Af[cur];
        const ushort* Bb = lds.st.Bs[cur];
        bf16x8 af[4], bfr[4];
        #pragma unroll
        for (int mi = 0; mi < 4; mi++) {
            int row = wr * 64 + mi * 16 + rl;
            int s = row & 7;
            int ulo = row * 8 + ((2 * g) ^ s);
            int uhi = row * 8 + ((2 * g + 1) ^ s);
            f32x4 xlo = *(const f32x4*)&Ab[ulo * 4];
            f32x4 xhi = *(const f32x4*)&Ab[uhi * 4];
            uint4 w; w.x = pk(xlo[0], xlo[1]); w.y = pk(xlo[2], xlo[3]);
            w.z = pk(xhi[0], xhi[1]); w.w = pk(xhi[2], xhi[3]);
            union { uint4 u; bf16x8 b; } cv; cv.u = w;
            af[mi] = cv.b;
        }
        #pragma unroll
        for (int ni = 0; ni < 4; ni++)
            bfr[ni] = *(const bf16x8*)&Bb[(wc * 64 + ni * 16 + rl) * 32 + oc * 8];
        __builtin_amdgcn_s_setprio(1);
        #pragma unroll
        for (int mi = 0; mi < 4; mi++)
            #pragma unroll
            for (int ni = 0; ni < 4; ni++)
                acc[mi][ni] = __builtin_amdgcn_mfma_f32_16x16x32_bf16(af[mi], bfr[ni], acc[mi][ni], 0, 0, 0);
        __builtin_amdgcn_s_setprio(0);
        asm volatile("s_waitcnt lgkmcnt(0)" ::: "memory");
        __builtin_amdgcn_s_barrier();
        cur ^= 1;
    }

    #pragma unroll
    for (int p = 0; p < 2; p++) {
        __syncthreads();
        if (wr == p) {
            #pragma unroll
            for (int mi = 0; mi < 4; mi++)
                #pragma unroll
                for (int ni = 0; ni < 4; ni++) {
                    int nl = wc * 64 + ni * 16 + (lane & 15);
                    int ml = mi * 16 + (lane >> 4) * 4;
                    uint2 w2;
                    w2.x = pk(acc[mi][ni][0], acc[mi][ni][1]);
                    w2.y = pk(acc[mi][ni][2], acc[mi][ni][3]);
                    *(uint2*)&lds.C[nl * 72 + ml] = w2;
                }
        }
        __syncthreads();
        {
            int r = tid >> 1, half = tid & 1;
            const uint4* src = (const uint4*)&lds.C[r * 72 + half * 32];
            ushort* dst = ET + (size_t)(n0 + r) * V_ + m0 + p * 64 + half * 32;
            uint4 v0 = src[0], v1 = src[1], v2 = src[2], v3 = src[3];
            *(uint4*)(dst + 0) = v0; *(uint4*)(dst + 8) = v1;
            *(uint4*)(dst + 16) = v2; *(uint4*)(dst + 24) = v3;
        }
    }
}

// ---------------- GEMM2 (bf16 MFMA, split-K=25, counted-vmcnt pipeline) ----------------
__global__ __launch_bounds__(256) void k_gemm2(const float* __restrict__ A,
                                               const ushort* __restrict__ ET,
                                               float* __restrict__ Cp) {
    __shared__ float Af[2][128 * 32];
    __shared__ ushort Bs[2][128 * 32];
    const int tid = threadIdx.x, lane = tid & 63, wid = tid >> 6;
    const int wr = wid >> 1, wc = wid & 1;
    const int m0 = blockIdx.x * 128, n0 = blockIdx.y * 128, kz = blockIdx.z;
    const size_t kbase = (size_t)kz * KCH2;

    const float* asrc[4];
    #pragma unroll
    for (int i = 0; i < 4; i++) {
        int u = i * 256 + tid;
        int r = u >> 3, c = (u & 7) ^ (r & 7);
        int rm = m0 + r; if (rm > S_ - 1) rm = S_ - 1;
        asrc[i] = A + (size_t)rm * V_ + kbase + c * 4;
    }
    const int u0 = tid, rb0 = u0 >> 2, ob0 = (u0 & 3) ^ ((rb0 >> 1) & 3);
    const int u1 = tid + 256, rb1 = u1 >> 2, ob1 = (u1 & 3) ^ ((rb1 >> 1) & 3);
    const ushort* bp0 = ET + (size_t)(n0 + rb0) * V_ + kbase + ob0 * 8;
    const ushort* bp1 = ET + (size_t)(n0 + rb1) * V_ + kbase + ob1 * 8;

    const int rl = lane & 15, g = lane >> 4;
    const int oB = g ^ ((rl >> 1) & 3);

    f32x4 acc[4][4];
    #pragma unroll
    for (int i = 0; i < 4; i++)
        #pragma unroll
        for (int j = 0; j < 4; j++) acc[i][j] = (f32x4){0.f, 0.f, 0.f, 0.f};

    gl16(bp0, &Bs[0][u0 * 8]);
    gl16(bp1, &Bs[0][u1 * 8]);
    #pragma unroll
    for (int i = 0; i < 4; i++) gl16(asrc[i], &Af[0][(i * 256 + tid) * 4]);
    __syncthreads();

    int cur = 0;
    constexpr int NT = KCH2 / 32;  // 40
    for (int t = 0; t < NT; ++t) {
        if (t + 1 < NT) {
            const int o = (t + 1) * 32;
            gl16(bp0 + o, &Bs[cur ^ 1][u0 * 8]);
            gl16(bp1 + o, &Bs[cur ^ 1][u1 * 8]);
            #pragma unroll
            for (int i = 0; i < 4; i++) gl16(asrc[i] + o, &Af[cur ^ 1][(i * 256 + tid) * 4]);
            asm volatile("s_waitcnt vmcnt(6)" ::: "memory");
        } else {
            asm volatile("s_waitcnt vmcnt(0)" ::: "memory");
        }
        __builtin_amdgcn_s_barrier();
        asm volatile("" ::: "memory");
        const float* Ab = Af[cur];
        const ushort* Bb = Bs[cur];
        bf16x8 af[4], bfr[4];
        #pragma unroll
        for (int mi = 0; mi < 4; mi++) {
            int row = wr * 64 + mi * 16 + rl;
            int s = row & 7;
            int ulo = row * 8 + ((2 * g) ^ s);
            int uhi = row * 8 + ((2 * g + 1) ^ s);
            f32x4 xlo = *(const f32x4*)&Ab[ulo * 4];
            f32x4 xhi = *(const f32x4*)&Ab[uhi * 4];
            uint4 w; w.x = pk(xlo[0], xlo[1]); w.y = pk(xlo[2], xlo[3]);
            w.z = pk(xhi[0], xhi[1]); w.w = pk(xhi[2], xhi[3]);
            union { uint4 u; bf16x8 b; } cv; cv.u = w;
            af[mi] = cv.b;
        }
        #pragma unroll
        for (int ni = 0; ni < 4; ni++)
            bfr[ni] = *(const bf16x8*)&Bb[(wc * 64 + ni * 16 + rl) * 32 + oB * 8];
        __builtin_amdgcn_s_setprio(1);
        #pragma unroll
        for (int mi = 0; mi < 4; mi++)
            #pragma unroll
            for (int ni = 0; ni < 4; ni++)
                acc[mi][ni] = __builtin_amdgcn_mfma_f32_16x16x32_bf16(af[mi], bfr[ni], acc[mi][ni], 0, 0, 0);
        __builtin_amdgcn_s_setprio(0);
        asm volatile("s_waitcnt lgkmcnt(0)" ::: "memory");
        __builtin_amdgcn_s_barrier();
        cur ^= 1;
    }

    #pragma unroll
    for (int mi = 0; mi < 4; mi++)
        #pragma unroll
        for (int ni = 0; ni < 4; ni++)
            #pragma unroll
            for (int j = 0; j < 4; j++) {
                int m = m0 + wr * 64 + mi * 16 + (lane >> 4) * 4 + j;
                int n = n0 + wc * 64 + ni * 16 + (lane & 15);
                if (m < S_) Cp[((size_t)kz * S_ + m) * 512 + n] = acc[mi][ni][j];
            }
}

// ---------------- reduce split-K + bias -> K bf16 [1024][256] and V^T bf16 [256][1024] ----------------
__global__ __launch_bounds__(256) void k_red(const float* __restrict__ Cp,
                                             const float* __restrict__ mb,
                                             const float* __restrict__ wsum,
                                             const float* __restrict__ bk,
                                             const float* __restrict__ bv,
                                             ushort* __restrict__ Kb,
                                             ushort* __restrict__ Vt) {
    int idx = blockIdx.x * 256 + threadIdx.x;   // over SP_*512
    if (idx >= SP_ * 512) return;
    int m = idx >> 9, n = idx & 511;
    float s = 0.f;
    if (m < S_) {
        #pragma unroll
        for (int z = 0; z < KSPLIT2; z++) s += Cp[(size_t)z * S_ * 512 + (size_t)m * 512 + n];
        float bias = (n < HF_) ? bk[n] : bv[n - HF_];
        s += mb[m] * wsum[n] + bias;
    }
    ushort h = f2bf(s);
    if (n < HF_) Kb[(size_t)m * HF_ + n] = h;
    else Vt[(size_t)(n - HF_) * SP_ + m] = h;
}

// ---------------- flash attention (MFMA, double-buffered K/V) per (h, bn) ----------------
__global__ __launch_bounds__(256) void k_attn(const float* __restrict__ q,
                                              const ushort* __restrict__ Kb,
                                              const ushort* __restrict__ Vt,
                                              float* __restrict__ rep) {
    const int h = blockIdx.x, bn = blockIdx.y;
    __shared__ ushort Ks[2][64 * 32];  // [row][oct ^ ((row>>1)&3)]
    __shared__ ushort Vs[2][32 * 64];  // V^T tile: [erow][soct ^ (erow&7)]
    __shared__ float  Ps[4][16 * 64];  // per-wave P
    const int tid = threadIdx.x, lane = tid & 63, w = tid >> 6;
    const int rl = lane & 15, g = lane >> 4;

    const int krow = tid >> 2, koc = (tid & 3) ^ ((krow >> 1) & 3);
    const ushort* ksrc = Kb + (size_t)krow * HF_ + h * 32 + koc * 8;
    const int verow = tid >> 3, vso = (tid & 7) ^ (verow & 7);
    const ushort* vsrc = Vt + (size_t)(h * 32 + verow) * SP_ + vso * 8;

    bf16x8 qf;
    {
        const float* qp = q + ((size_t)bn * L_ + w * 16 + rl) * HF_ + h * 32 + g * 8;
        float4 x = *(const float4*)qp, y = *(const float4*)(qp + 4);
        uint4 u; u.x = pk(x.x, x.y); u.y = pk(x.z, x.w); u.z = pk(y.x, y.y); u.w = pk(y.z, y.w);
        union { uint4 u4; bf16x8 b; } cv; cv.u4 = u; qf = cv.b;
    }

    float mrow[4] = {-1e30f, -1e30f, -1e30f, -1e30f};
    float rsum[4] = {0.f, 0.f, 0.f, 0.f};
    f32x4 oacc[2] = {(f32x4){0,0,0,0}, (f32x4){0,0,0,0}};
    float* Pw = Ps[w];

    // prologue: stage tile 0
    gl16(ksrc, &Ks[0][tid * 8]);
    gl16(vsrc, &Vs[0][tid * 8]);
    __syncthreads();

    int cur = 0;
    for (int t = 0; t < 16; ++t) {
        if (t + 1 < 16) {
            gl16(ksrc + (size_t)(t + 1) * 64 * HF_, &Ks[cur ^ 1][tid * 8]);
            gl16(vsrc + (t + 1) * 64, &Vs[cur ^ 1][tid * 8]);
            asm volatile("s_waitcnt vmcnt(2)" ::: "memory");
        } else {
            asm volatile("s_waitcnt vmcnt(0)" ::: "memory");
        }
        __builtin_amdgcn_s_barrier();
        asm volatile("" ::: "memory");
        const int s0 = t * 64;

        f32x4 sc[4];
        __builtin_amdgcn_s_setprio(1);
        #pragma unroll
        for (int nf = 0; nf < 4; nf++) {
            const int row = nf * 16 + rl;
            bf16x8 kf = *(const bf16x8*)&Ks[cur][(row * 4 + (g ^ ((rl >> 1) & 3))) * 8];
            sc[nf] = __builtin_amdgcn_mfma_f32_16x16x32_bf16(qf, kf, (f32x4){0, 0, 0, 0}, 0, 0, 0);
            if (s0 + row >= S_) sc[nf] = (f32x4){-1e30f, -1e30f, -1e30f, -1e30f};
        }
        __builtin_amdgcn_s_setprio(0);
        float tmax[4];
        #pragma unroll
        for (int j = 0; j < 4; j++)
            tmax[j] = fmaxf(fmaxf(sc[0][j], sc[1][j]), fmaxf(sc[2][j], sc[3][j]));
        #pragma unroll
        for (int d = 1; d < 16; d <<= 1)
            #pragma unroll
            for (int j = 0; j < 4; j++) tmax[j] = fmaxf(tmax[j], __shfl_xor(tmax[j], d, 64));
        float resc[4];
        #pragma unroll
        for (int j = 0; j < 4; j++) {
            float mn = fmaxf(mrow[j], tmax[j]);
            resc[j] = __expf(mrow[j] - mn);
            mrow[j] = mn;
            rsum[j] *= resc[j];
            oacc[0][j] *= resc[j];
            oacc[1][j] *= resc[j];
        }
        #pragma unroll
        for (int nf = 0; nf < 4; nf++) {
            const int s = nf * 16 + rl;
            #pragma unroll
            for (int j = 0; j < 4; j++) {
                float p = __expf(sc[nf][j] - mrow[j]);
                float pf = __uint_as_float(((uint)f2bf(p)) << 16);
                rsum[j] += pf;
                const int row = 4 * g + j;
                Pw[row * 64 + (((s >> 2) ^ row) << 2) + (s & 3)] = pf;
            }
        }
        __builtin_amdgcn_s_setprio(1);
        #pragma unroll
        for (int h2 = 0; h2 < 2; h2++) {
            const int q1 = (h2 * 8 + 2 * g) ^ rl;
            const int q2 = (h2 * 8 + 2 * g + 1) ^ rl;
            f32x4 plo = *(const f32x4*)&Pw[rl * 64 + q1 * 4];
            f32x4 phi = *(const f32x4*)&Pw[rl * 64 + q2 * 4];
            uint4 pu; pu.x = pk(plo[0], plo[1]); pu.y = pk(plo[2], plo[3]);
            pu.z = pk(phi[0], phi[1]); pu.w = pk(phi[2], phi[3]);
            union { uint4 u; bf16x8 b; } cv; cv.u = pu;
            bf16x8 pa = cv.b;
            #pragma unroll
            for (int eg = 0; eg < 2; eg++) {
                const int erow = eg * 16 + rl;
                const int su = (h2 * 4 + g) ^ (erow & 7);
                bf16x8 vf = *(const bf16x8*)&Vs[cur][erow * 64 + su * 8];
                oacc[eg] = __builtin_amdgcn_mfma_f32_16x16x32_bf16(pa, vf, oacc[eg], 0, 0, 0);
            }
        }
        __builtin_amdgcn_s_setprio(0);
        asm volatile("s_waitcnt lgkmcnt(0)" ::: "memory");
        __builtin_amdgcn_s_barrier();
        cur ^= 1;
    }

    #pragma unroll
    for (int d = 1; d < 16; d <<= 1)
        #pragma unroll
        for (int j = 0; j < 4; j++) rsum[j] += __shfl_xor(rsum[j], d, 64);
    float inv[4];
    #pragma unroll
    for (int j = 0; j < 4; j++) inv[j] = 1.0f / rsum[j];
    #pragma unroll
    for (int eg = 0; eg < 2; eg++)
        #pragma unroll
        for (int j = 0; j < 4; j++)
            rep[((size_t)bn * HF_ + h * 32 + eg * 16 + rl) * 64 + w * 16 + 4 * g + j] =
                oacc[eg][j] * inv[j];
}

// ---------------- fused: out-projection + head GEMM + de-normalize ----------------
__global__ __launch_bounds__(256) void k_post(const float* __restrict__ rep,
                                              const float* __restrict__ wo,
                                              const float* __restrict__ bo,
                                              const float* __restrict__ hw,
                                              const float* __restrict__ hb,
                                              const float* __restrict__ mean_i,
                                              const float* __restrict__ std_i,
                                              float* __restrict__ out) {
    const int bn = blockIdx.x, b = bn / N_, n = bn % N_;
    __shared__ float woT[HF_ * 32];  // [c][e]
    __shared__ float dt[2048];       // out32 [l][e]
    const int tid = threadIdx.x;
    for (int idx = tid; idx < HF_ * 32; idx += 256) {
        int e = idx & 31, c = idx >> 5;
        woT[c * 32 + e] = wo[(size_t)e * HF_ + c];
    }
    __syncthreads();
    {
        const int l = tid & 63, e0 = (tid >> 6) * 8;
        float acc[8];
        #pragma unroll
        for (int i = 0; i < 8; i++) acc[i] = bo[e0 + i];
        const float* rp = rep + (size_t)bn * HF_ * 64 + l;
        for (int c = 0; c < HF_; c++) {
            float rv = rp[(size_t)c * 64];
            #pragma unroll
            for (int i = 0; i < 8; i++) acc[i] += rv * woT[c * 32 + e0 + i];
        }
        #pragma unroll
        for (int i = 0; i < 8; i++) dt[l * 32 + e0 + i] = acc[i];
    }
    __syncthreads();
    const float m = mean_i[bn], sd = std_i[bn];
    for (int p = tid; p < PRED_; p += 256) {
        float acc = hb[p];
        const float* w = hw + (size_t)p * HNF_;
        for (int f = 0; f < DFF_; f++) {
            const float* wf = w + f * 64;
            #pragma unroll
            for (int ll = 0; ll < 64; ll++) acc += dt[ll * 32 + f] * wf[ll];
        }
        out[(size_t)b * PRED_ * N_ + (size_t)p * N_ + n] = acc * sd + m;
    }
}

extern "C" void kernel_launch(void* const* d_in, const int* in_sizes, int n_in,
                              void* d_out, int out_size, void* d_ws, size_t ws_size,
                              hipStream_t stream) {
    const float* x_enc   = (const float*)d_in[0];
    const float* conv_w  = (const float*)d_in[1];
    const float* word_emb= (const float*)d_in[2];
    const float* map_w   = (const float*)d_in[3];
    const float* map_b   = (const float*)d_in[4];
    const float* wq      = (const float*)d_in[5];
    const float* bq      = (const float*)d_in[6];
    const float* wk      = (const float*)d_in[7];
    const float* bk      = (const float*)d_in[8];
    const float* wv      = (const float*)d_in[9];
    const float* bv      = (const float*)d_in[10];
    const float* wo      = (const float*)d_in[11];
    const float* bo      = (const float*)d_in[12];
    const float* head_w  = (const float*)d_in[13];
    const float* head_b  = (const float*)d_in[14];

    float* ws = (float*)d_ws;
    float* mean_w = ws;                          // 256
    float* std_w  = ws + 256;                    // 256
    float* wsum_w = ws + 512;                    // 512
    float* q_w    = ws + 1024;                   // 224*16384
    float* kv_w   = q_w + (size_t)BN_ * L_ * HF_;// 2 MB region for bf16 K/V^T
    float* cp_w   = kv_w + (size_t)S_ * 512;     // 25*1000*512 (51.2 MB)
    float* rep_w  = cp_w;                        // alias: cp dead after k_red
    ushort* et_w  = (ushort*)(cp_w + (size_t)KSPLIT2 * S_ * 512);  // 512*32000 bf16
    ushort* wkv_w = et_w + (size_t)512 * V_;                       // 512*4096 bf16
    ushort* kb_w  = (ushort*)kv_w;               // [1024][256] bf16 (512 KB)
    ushort* vt_w  = kb_w + (size_t)SP_ * HF_;    // [256][1024] bf16 (512 KB)

    k_pre<<<BN_, 256, 0, stream>>>(x_enc, conv_w, wq, bq, mean_w, std_w, q_w);
    k_wsum<<<512, 256, 0, stream>>>(wk, wv, wsum_w);
    k_cvt_wkv<<<(512 * DLLM_ / 8) / 256, 256, 0, stream>>>(wk, wv, wkv_w);
    k_gemm1<<<dim3(2, V_ / 128), 512, 0, stream>>>(word_emb, wkv_w, et_w);
    k_gemm2<<<dim3(8, 4, KSPLIT2), 256, 0, stream>>>(map_w, et_w, cp_w);
    k_red<<<(SP_ * 512) / 256, 256, 0, stream>>>(cp_w, map_b, wsum_w, bk, bv, kb_w, vt_w);
    k_attn<<<dim3(NH_, BN_), 256, 0, stream>>>(q_w, kb_w, vt_w, rep_w);
    k_post<<<BN_, 256, 0, stream>>>(rep_w, wo, bo, head_w, head_b, mean_w, std_w, (float*)d_out);
}

// Round 11
// 536.561 us; speedup vs baseline: 1.0348x; 1.0348x over previous
//
#include <hip/hip_runtime.h>
#include <math.h>

constexpr int B_ = 32, T_ = 512, N_ = 7, BN_ = 224;
constexpr int L_ = 64, DM_ = 32, PLEN_ = 16;
constexpr int HF_ = 256, NH_ = 8, DFF_ = 32;
constexpr int S_ = 1000, SP_ = 1024, DLLM_ = 4096, V_ = 32000;
constexpr int PRED_ = 96, HNF_ = 2048;
constexpr int KSPLIT2 = 25, KCH2 = 1280;  // GEMM2 split-K: 25 * 1280 = 32000

typedef short bf16x8 __attribute__((ext_vector_type(8)));
typedef float f32x4 __attribute__((ext_vector_type(4)));

__device__ inline ushort f2bf(float x) {
    union { float f; uint u; } v; v.f = x;
    uint r = v.u + 0x7fffu + ((v.u >> 16) & 1u);  // RNE
    return (ushort)(r >> 16);
}
__device__ inline uint pk(float a, float b) {
    return (uint)f2bf(a) | ((uint)f2bf(b) << 16);
}
__device__ inline void gl16(const void* g, void* l) {
    __builtin_amdgcn_global_load_lds(
        (const __attribute__((address_space(1))) void*)g,
        (__attribute__((address_space(3))) void*)l, 16, 0, 0);
}

// ---------------- fused: stats + normalize + conv embed + q-projection ----------------
__global__ __launch_bounds__(256) void k_pre(const float* __restrict__ x,
                                             const float* __restrict__ conv_w,
                                             const float* __restrict__ wq,
                                             const float* __restrict__ bq,
                                             float* __restrict__ mean_o,
                                             float* __restrict__ std_o,
                                             float* __restrict__ qo) {
    const int bn = blockIdx.x, b = bn / N_, n = bn % N_;
    __shared__ float xn[520];
    __shared__ float cw[DM_ * PLEN_ * 3];
    __shared__ float enc_s[2048];
    __shared__ float wqs[HF_ * DM_];
    __shared__ float rs[4], rq[4], sm2[2];
    const int tid = threadIdx.x;
    const float* xp = x + (size_t)b * T_ * N_ + n;

    float s = 0.f, sq = 0.f;
    for (int t = tid; t < T_; t += 256) { float v = xp[(size_t)t * N_]; s += v; sq += v * v; }
    for (int i = tid; i < DM_ * PLEN_ * 3; i += 256) cw[i] = conv_w[i];
    for (int i = tid; i < HF_ * DM_; i += 256) wqs[i] = wq[i];
    for (int o = 32; o > 0; o >>= 1) { s += __shfl_down(s, o, 64); sq += __shfl_down(sq, o, 64); }
    int wid = tid >> 6, lane = tid & 63;
    if (lane == 0) { rs[wid] = s; rq[wid] = sq; }
    __syncthreads();
    if (tid == 0) {
        float S = rs[0] + rs[1] + rs[2] + rs[3];
        float Q = rq[0] + rq[1] + rq[2] + rq[3];
        float m = S / T_;
        float var = Q / T_ - m * m;
        float sd = sqrtf(var + 1e-5f);
        mean_o[bn] = m; std_o[bn] = sd;
        sm2[0] = m; sm2[1] = sd;
    }
    __syncthreads();
    const float m = sm2[0], rstd = 1.0f / sm2[1];
    for (int t = tid; t < T_; t += 256) xn[t] = (xp[(size_t)t * N_] - m) * rstd;
    __syncthreads();
    if (tid < 8) xn[T_ + tid] = xn[T_ - 1];
    __syncthreads();
    for (int idx = tid; idx < L_ * DM_; idx += 256) {
        int l = idx >> 5, o = idx & 31;
        float acc = 0.f;
        #pragma unroll
        for (int t = 0; t < 3; t++) {
            int col = l + t;
            int pcol = (col == 0) ? 63 : ((col == 65) ? 0 : col - 1);
            const float* xb = &xn[pcol * 8];
            const float* cwb = &cw[o * 48 + t];
            #pragma unroll
            for (int i = 0; i < 16; i++) acc += xb[i] * cwb[i * 3];
        }
        enc_s[idx] = acc;
    }
    __syncthreads();
    const float scale = 0.17677669529663687f;  // 1/sqrt(32)
    for (int idx = tid; idx < L_ * HF_; idx += 256) {
        int l = idx >> 8, c = idx & 255;
        float acc = bq[c];
        const float* e = &enc_s[l * 32];
        const float* w = &wqs[c * 32];
        #pragma unroll
        for (int k = 0; k < 32; k++) acc += e[k] * w[k];
        qo[(size_t)bn * L_ * HF_ + idx] = acc * scale;
    }
}

// ---------------- wsum[c] = sum_d wkv[c][d] (exact f32, for map_b folding) ----------------
__global__ __launch_bounds__(256) void k_wsum(const float* __restrict__ wk,
                                              const float* __restrict__ wv,
                                              float* __restrict__ wsum) {
    int c = blockIdx.x;
    const float* row = (c < HF_) ? wk + (size_t)c * DLLM_ : wv + (size_t)(c - HF_) * DLLM_;
    float s = 0.f;
    for (int d = threadIdx.x; d < DLLM_; d += 256) s += row[d];
    for (int o = 32; o > 0; o >>= 1) s += __shfl_down(s, o, 64);
    __shared__ float rs[4];
    int wid = threadIdx.x >> 6, lane = threadIdx.x & 63;
    if (lane == 0) rs[wid] = s;
    __syncthreads();
    if (threadIdx.x == 0) wsum[c] = rs[0] + rs[1] + rs[2] + rs[3];
}

// ---------------- cvt wk,wv -> wkv_bf [512][4096] bf16 ----------------
__global__ __launch_bounds__(256) void k_cvt_wkv(const float* __restrict__ wk,
                                                 const float* __restrict__ wv,
                                                 ushort* __restrict__ out) {
    int g = blockIdx.x * 256 + threadIdx.x;
    int e = g * 8;
    const float* src = (e < HF_ * DLLM_) ? wk + e : wv + (e - HF_ * DLLM_);
    float4 x = *(const float4*)src, y = *(const float4*)(src + 4);
    uint4 w; w.x = pk(x.x, x.y); w.y = pk(x.z, x.w); w.z = pk(y.x, y.y); w.w = pk(y.z, y.w);
    *(uint4*)(out + e) = w;
}

// ---------------- GEMM1 (bf16 MFMA, robust pipeline, reg-pack A once) ----------------
// E_T[512][32000] = (word_emb @ wkv^T)^T. BM=128, BN=256, BK=32, 512 thr (8 waves 2x4).
// Iter t: issue A(t+1) reg loads + B(t+1) gl16 early; ds_read+MFMA tile t; pack A(t+1)
// -> bf16 LDS; vmcnt(0)+lgkmcnt(0)+barrier (no queue-order assumptions).
__global__ __launch_bounds__(512) void k_gemm1(const float* __restrict__ A,
                                               const ushort* __restrict__ Bw,
                                               ushort* __restrict__ ET) {
    __shared__ union {
        struct { ushort A2[2][128 * 32]; ushort Bs[2][256 * 32]; } st;  // 48 KB
        ushort C[256 * 72];                                             // 36 KB epilogue
    } lds;
    const int tid = threadIdx.x;
    const int lane = tid & 63, wid = tid >> 6;
    const int wr = wid >> 2, wc = wid & 3;
    const int n0 = blockIdx.x * 256, m0 = blockIdx.y * 128;

    // A stager: thread t -> row ar=t>>2, octet ao=t&3; LDS unit au (swizzled, 2-way-free)
    const int ar = tid >> 2, ao = tid & 3;
    const int au = (ar << 2) | (ao ^ ((ar >> 1) & 3));
    const float* aptr = A + (size_t)(m0 + ar) * DLLM_ + ao * 8;

    // B stager: units u0=tid, u1=tid+512; source octet pre-swizzled
    const int u0 = tid, rb0 = u0 >> 2, ob0 = (u0 & 3) ^ ((rb0 >> 1) & 3);
    const int u1 = tid + 512, rb1 = u1 >> 2, ob1 = (u1 & 3) ^ ((rb1 >> 1) & 3);
    const ushort* bptr0 = Bw + (size_t)(n0 + rb0) * DLLM_ + ob0 * 8;
    const ushort* bptr1 = Bw + (size_t)(n0 + rb1) * DLLM_ + ob1 * 8;

    const int rl = lane & 15, g = lane >> 4;
    const int oc = g ^ ((rl >> 1) & 3);   // shared read swizzle (A unit & B oct)

    f32x4 acc[4][4];
    #pragma unroll
    for (int i = 0; i < 4; i++)
        #pragma unroll
        for (int j = 0; j < 4; j++) acc[i][j] = (f32x4){0.f, 0.f, 0.f, 0.f};

    // prologue: A(0) regs -> pack -> buf0; B(0) gl16 -> buf0; full drain
    float4 pa0 = *(const float4*)aptr;
    float4 pa1 = *(const float4*)(aptr + 4);
    gl16(bptr0, &lds.st.Bs[0][u0 * 8]);
    gl16(bptr1, &lds.st.Bs[0][u1 * 8]);
    {
        uint4 wa; wa.x = pk(pa0.x, pa0.y); wa.y = pk(pa0.z, pa0.w);
        wa.z = pk(pa1.x, pa1.y); wa.w = pk(pa1.z, pa1.w);
        *(uint4*)&lds.st.A2[0][au * 8] = wa;
    }
    __syncthreads();

    int cur = 0;
    constexpr int NT = DLLM_ / 32;  // 128
    for (int t = 0; t < NT; ++t) {
        const bool more = (t + 1 < NT);
        if (more) {
            const int o = (t + 1) * 32;
            const float* ap = aptr + o;
            pa0 = *(const float4*)ap;          // A(t+1) loads, in flight over MFMA
            pa1 = *(const float4*)(ap + 4);
            gl16(bptr0 + o, &lds.st.Bs[cur ^ 1][u0 * 8]);
            gl16(bptr1 + o, &lds.st.Bs[cur ^ 1][u1 * 8]);
        }
        const ushort* Ab = lds.st.A2[cur];
        const ushort* Bb = lds.st.Bs[cur];
        bf16x8 af[4], bfr[4];
        #pragma unroll
        for (int mi = 0; mi < 4; mi++) {
            int row = wr * 64 + mi * 16 + rl;
            af[mi] = *(const bf16x8*)&Ab[(row * 4 + oc) * 8];
        }
        #pragma unroll
        for (int ni = 0; ni < 4; ni++)
            bfr[ni] = *(const bf16x8*)&Bb[(wc * 64 + ni * 16 + rl) * 32 + oc * 8];
        __builtin_amdgcn_s_setprio(1);
        #pragma unroll
        for (int mi = 0; mi < 4; mi++)
            #pragma unroll
            for (int ni = 0; ni < 4; ni++)
                acc[mi][ni] = __builtin_amdgcn_mfma_f32_16x16x32_bf16(af[mi], bfr[ni], acc[mi][ni], 0, 0, 0);
        __builtin_amdgcn_s_setprio(0);
        if (more) {
            // pack A(t+1) once (compiler auto-waits pa regs) -> buf^1
            uint4 wa; wa.x = pk(pa0.x, pa0.y); wa.y = pk(pa0.z, pa0.w);
            wa.z = pk(pa1.x, pa1.y); wa.w = pk(pa1.z, pa1.w);
            *(uint4*)&lds.st.A2[cur ^ 1][au * 8] = wa;
        }
        // full drain: B(t+1) landed, my ds ops retired; no issue-order assumptions
        asm volatile("s_waitcnt vmcnt(0) lgkmcnt(0)" ::: "memory");
        __builtin_amdgcn_s_barrier();
        asm volatile("" ::: "memory");
        cur ^= 1;
    }

    // epilogue: transpose to E_T via LDS, two rounds over wr halves
    #pragma unroll
    for (int p = 0; p < 2; p++) {
        __syncthreads();
        if (wr == p) {
            #pragma unroll
            for (int mi = 0; mi < 4; mi++)
                #pragma unroll
                for (int ni = 0; ni < 4; ni++) {
                    int nl = wc * 64 + ni * 16 + (lane & 15);
                    int ml = mi * 16 + (lane >> 4) * 4;
                    uint2 w2;
                    w2.x = pk(acc[mi][ni][0], acc[mi][ni][1]);
                    w2.y = pk(acc[mi][ni][2], acc[mi][ni][3]);
                    *(uint2*)&lds.C[nl * 72 + ml] = w2;
                }
        }
        __syncthreads();
        {
            int r = tid >> 1, half = tid & 1;
            const uint4* src = (const uint4*)&lds.C[r * 72 + half * 32];
            ushort* dst = ET + (size_t)(n0 + r) * V_ + m0 + p * 64 + half * 32;
            uint4 v0 = src[0], v1 = src[1], v2 = src[2], v3 = src[3];
            *(uint4*)(dst + 0) = v0; *(uint4*)(dst + 8) = v1;
            *(uint4*)(dst + 16) = v2; *(uint4*)(dst + 24) = v3;
        }
    }
}

// ---------------- GEMM2 (bf16 MFMA, split-K=25, counted-vmcnt pipeline; all-gl16) ----------------
__global__ __launch_bounds__(256) void k_gemm2(const float* __restrict__ A,
                                               const ushort* __restrict__ ET,
                                               float* __restrict__ Cp) {
    __shared__ float Af[2][128 * 32];
    __shared__ ushort Bs[2][128 * 32];
    const int tid = threadIdx.x, lane = tid & 63, wid = tid >> 6;
    const int wr = wid >> 1, wc = wid & 1;
    const int m0 = blockIdx.x * 128, n0 = blockIdx.y * 128, kz = blockIdx.z;
    const size_t kbase = (size_t)kz * KCH2;

    const float* asrc[4];
    #pragma unroll
    for (int i = 0; i < 4; i++) {
        int u = i * 256 + tid;
        int r = u >> 3, c = (u & 7) ^ (r & 7);
        int rm = m0 + r; if (rm > S_ - 1) rm = S_ - 1;
        asrc[i] = A + (size_t)rm * V_ + kbase + c * 4;
    }
    const int u0 = tid, rb0 = u0 >> 2, ob0 = (u0 & 3) ^ ((rb0 >> 1) & 3);
    const int u1 = tid + 256, rb1 = u1 >> 2, ob1 = (u1 & 3) ^ ((rb1 >> 1) & 3);
    const ushort* bp0 = ET + (size_t)(n0 + rb0) * V_ + kbase + ob0 * 8;
    const ushort* bp1 = ET + (size_t)(n0 + rb1) * V_ + kbase + ob1 * 8;

    const int rl = lane & 15, g = lane >> 4;
    const int oB = g ^ ((rl >> 1) & 3);

    f32x4 acc[4][4];
    #pragma unroll
    for (int i = 0; i < 4; i++)
        #pragma unroll
        for (int j = 0; j < 4; j++) acc[i][j] = (f32x4){0.f, 0.f, 0.f, 0.f};

    gl16(bp0, &Bs[0][u0 * 8]);
    gl16(bp1, &Bs[0][u1 * 8]);
    #pragma unroll
    for (int i = 0; i < 4; i++) gl16(asrc[i], &Af[0][(i * 256 + tid) * 4]);
    __syncthreads();

    int cur = 0;
    constexpr int NT = KCH2 / 32;  // 40
    for (int t = 0; t < NT; ++t) {
        if (t + 1 < NT) {
            const int o = (t + 1) * 32;
            gl16(bp0 + o, &Bs[cur ^ 1][u0 * 8]);
            gl16(bp1 + o, &Bs[cur ^ 1][u1 * 8]);
            #pragma unroll
            for (int i = 0; i < 4; i++) gl16(asrc[i] + o, &Af[cur ^ 1][(i * 256 + tid) * 4]);
            asm volatile("s_waitcnt vmcnt(6)" ::: "memory");
        } else {
            asm volatile("s_waitcnt vmcnt(0)" ::: "memory");
        }
        __builtin_amdgcn_s_barrier();
        asm volatile("" ::: "memory");
        const float* Ab = Af[cur];
        const ushort* Bb = Bs[cur];
        bf16x8 af[4], bfr[4];
        #pragma unroll
        for (int mi = 0; mi < 4; mi++) {
            int row = wr * 64 + mi * 16 + rl;
            int s = row & 7;
            int ulo = row * 8 + ((2 * g) ^ s);
            int uhi = row * 8 + ((2 * g + 1) ^ s);
            f32x4 xlo = *(const f32x4*)&Ab[ulo * 4];
            f32x4 xhi = *(const f32x4*)&Ab[uhi * 4];
            uint4 w; w.x = pk(xlo[0], xlo[1]); w.y = pk(xlo[2], xlo[3]);
            w.z = pk(xhi[0], xhi[1]); w.w = pk(xhi[2], xhi[3]);
            union { uint4 u; bf16x8 b; } cv; cv.u = w;
            af[mi] = cv.b;
        }
        #pragma unroll
        for (int ni = 0; ni < 4; ni++)
            bfr[ni] = *(const bf16x8*)&Bb[(wc * 64 + ni * 16 + rl) * 32 + oB * 8];
        __builtin_amdgcn_s_setprio(1);
        #pragma unroll
        for (int mi = 0; mi < 4; mi++)
            #pragma unroll
            for (int ni = 0; ni < 4; ni++)
                acc[mi][ni] = __builtin_amdgcn_mfma_f32_16x16x32_bf16(af[mi], bfr[ni], acc[mi][ni], 0, 0, 0);
        __builtin_amdgcn_s_setprio(0);
        asm volatile("s_waitcnt lgkmcnt(0)" ::: "memory");
        __builtin_amdgcn_s_barrier();
        cur ^= 1;
    }

    #pragma unroll
    for (int mi = 0; mi < 4; mi++)
        #pragma unroll
        for (int ni = 0; ni < 4; ni++)
            #pragma unroll
            for (int j = 0; j < 4; j++) {
                int m = m0 + wr * 64 + mi * 16 + (lane >> 4) * 4 + j;
                int n = n0 + wc * 64 + ni * 16 + (lane & 15);
                if (m < S_) Cp[((size_t)kz * S_ + m) * 512 + n] = acc[mi][ni][j];
            }
}

// ---------------- reduce split-K + bias -> K bf16 [1024][256] and V^T bf16 [256][1024] ----------------
__global__ __launch_bounds__(256) void k_red(const float* __restrict__ Cp,
                                             const float* __restrict__ mb,
                                             const float* __restrict__ wsum,
                                             const float* __restrict__ bk,
                                             const float* __restrict__ bv,
                                             ushort* __restrict__ Kb,
                                             ushort* __restrict__ Vt) {
    int idx = blockIdx.x * 256 + threadIdx.x;   // over SP_*512
    if (idx >= SP_ * 512) return;
    int m = idx >> 9, n = idx & 511;
    float s = 0.f;
    if (m < S_) {
        #pragma unroll
        for (int z = 0; z < KSPLIT2; z++) s += Cp[(size_t)z * S_ * 512 + (size_t)m * 512 + n];
        float bias = (n < HF_) ? bk[n] : bv[n - HF_];
        s += mb[m] * wsum[n] + bias;
    }
    ushort h = f2bf(s);
    if (n < HF_) Kb[(size_t)m * HF_ + n] = h;
    else Vt[(size_t)(n - HF_) * SP_ + m] = h;
}

// ---------------- flash attention (MFMA, single-buffered) per (h, bn) ----------------
__global__ __launch_bounds__(256) void k_attn(const float* __restrict__ q,
                                              const ushort* __restrict__ Kb,
                                              const ushort* __restrict__ Vt,
                                              float* __restrict__ rep) {
    const int h = blockIdx.x, bn = blockIdx.y;
    __shared__ ushort Ks[64 * 32];     // [row][oct ^ ((row>>1)&3)], 16B units
    __shared__ ushort Vs[32 * 64];     // V^T tile: [erow][soct ^ (erow&7)]
    __shared__ float  Ps[4][16 * 64];  // per-wave P
    const int tid = threadIdx.x, lane = tid & 63, w = tid >> 6;
    const int rl = lane & 15, g = lane >> 4;

    const int krow = tid >> 2, koc = (tid & 3) ^ ((krow >> 1) & 3);
    const ushort* ksrc = Kb + (size_t)krow * HF_ + h * 32 + koc * 8;
    ushort* kdst = &Ks[tid * 8];
    const int verow = tid >> 3, vso = (tid & 7) ^ (verow & 7);
    const ushort* vsrc = Vt + (size_t)(h * 32 + verow) * SP_ + vso * 8;
    ushort* vdst = &Vs[tid * 8];

    bf16x8 qf;
    {
        const float* qp = q + ((size_t)bn * L_ + w * 16 + rl) * HF_ + h * 32 + g * 8;
        float4 x = *(const float4*)qp, y = *(const float4*)(qp + 4);
        uint4 u; u.x = pk(x.x, x.y); u.y = pk(x.z, x.w); u.z = pk(y.x, y.y); u.w = pk(y.z, y.w);
        union { uint4 u4; bf16x8 b; } cv; cv.u4 = u; qf = cv.b;
    }

    float mrow[4] = {-1e30f, -1e30f, -1e30f, -1e30f};
    float rsum[4] = {0.f, 0.f, 0.f, 0.f};
    f32x4 oacc[2] = {(f32x4){0,0,0,0}, (f32x4){0,0,0,0}};
    float* Pw = Ps[w];

    for (int t = 0; t < 16; ++t) {
        const int s0 = t * 64;
        gl16(ksrc + (size_t)s0 * HF_, kdst);
        gl16(vsrc + s0, vdst);
        __syncthreads();

        f32x4 sc[4];
        __builtin_amdgcn_s_setprio(1);
        #pragma unroll
        for (int nf = 0; nf < 4; nf++) {
            const int row = nf * 16 + rl;
            bf16x8 kf = *(const bf16x8*)&Ks[(row * 4 + (g ^ ((rl >> 1) & 3))) * 8];
            sc[nf] = __builtin_amdgcn_mfma_f32_16x16x32_bf16(qf, kf, (f32x4){0, 0, 0, 0}, 0, 0, 0);
            if (s0 + row >= S_) sc[nf] = (f32x4){-1e30f, -1e30f, -1e30f, -1e30f};
        }
        __builtin_amdgcn_s_setprio(0);
        float tmax[4];
        #pragma unroll
        for (int j = 0; j < 4; j++)
            tmax[j] = fmaxf(fmaxf(sc[0][j], sc[1][j]), fmaxf(sc[2][j], sc[3][j]));
        #pragma unroll
        for (int d = 1; d < 16; d <<= 1)
            #pragma unroll
            for (int j = 0; j < 4; j++) tmax[j] = fmaxf(tmax[j], __shfl_xor(tmax[j], d, 64));
        float resc[4];
        #pragma unroll
        for (int j = 0; j < 4; j++) {
            float mn = fmaxf(mrow[j], tmax[j]);
            resc[j] = __expf(mrow[j] - mn);
            mrow[j] = mn;
            rsum[j] *= resc[j];
            oacc[0][j] *= resc[j];
            oacc[1][j] *= resc[j];
        }
        #pragma unroll
        for (int nf = 0; nf < 4; nf++) {
            const int s = nf * 16 + rl;
            #pragma unroll
            for (int j = 0; j < 4; j++) {
                float p = __expf(sc[nf][j] - mrow[j]);
                float pf = __uint_as_float(((uint)f2bf(p)) << 16);
                rsum[j] += pf;
                const int row = 4 * g + j;
                Pw[row * 64 + (((s >> 2) ^ row) << 2) + (s & 3)] = pf;
            }
        }
        __builtin_amdgcn_s_setprio(1);
        #pragma unroll
        for (int h2 = 0; h2 < 2; h2++) {
            const int q1 = (h2 * 8 + 2 * g) ^ rl;
            const int q2 = (h2 * 8 + 2 * g + 1) ^ rl;
            f32x4 plo = *(const f32x4*)&Pw[rl * 64 + q1 * 4];
            f32x4 phi = *(const f32x4*)&Pw[rl * 64 + q2 * 4];
            uint4 pu; pu.x = pk(plo[0], plo[1]); pu.y = pk(plo[2], plo[3]);
            pu.z = pk(phi[0], phi[1]); pu.w = pk(phi[2], phi[3]);
            union { uint4 u; bf16x8 b; } cv; cv.u = pu;
            bf16x8 pa = cv.b;
            #pragma unroll
            for (int eg = 0; eg < 2; eg++) {
                const int erow = eg * 16 + rl;
                const int su = (h2 * 4 + g) ^ (erow & 7);
                bf16x8 vf = *(const bf16x8*)&Vs[erow * 64 + su * 8];
                oacc[eg] = __builtin_amdgcn_mfma_f32_16x16x32_bf16(pa, vf, oacc[eg], 0, 0, 0);
            }
        }
        __builtin_amdgcn_s_setprio(0);
        __syncthreads();
    }

    #pragma unroll
    for (int d = 1; d < 16; d <<= 1)
        #pragma unroll
        for (int j = 0; j < 4; j++) rsum[j] += __shfl_xor(rsum[j], d, 64);
    float inv[4];
    #pragma unroll
    for (int j = 0; j < 4; j++) inv[j] = 1.0f / rsum[j];
    #pragma unroll
    for (int eg = 0; eg < 2; eg++)
        #pragma unroll
        for (int j = 0; j < 4; j++)
            rep[((size_t)bn * HF_ + h * 32 + eg * 16 + rl) * 64 + w * 16 + 4 * g + j] =
                oacc[eg][j] * inv[j];
}

// ---------------- fused: out-projection + head GEMM + de-normalize ----------------
__global__ __launch_bounds__(256) void k_post(const float* __restrict__ rep,
                                              const float* __restrict__ wo,
                                              const float* __restrict__ bo,
                                              const float* __restrict__ hw,
                                              const float* __restrict__ hb,
                                              const float* __restrict__ mean_i,
                                              const float* __restrict__ std_i,
                                              float* __restrict__ out) {
    const int bn = blockIdx.x, b = bn / N_, n = bn % N_;
    __shared__ float woT[HF_ * 32];  // [c][e]
    __shared__ float dt[2048];       // out32 [l][e]
    const int tid = threadIdx.x;
    for (int idx = tid; idx < HF_ * 32; idx += 256) {
        int e = idx & 31, c = idx >> 5;
        woT[c * 32 + e] = wo[(size_t)e * HF_ + c];
    }
    __syncthreads();
    {
        const int l = tid & 63, e0 = (tid >> 6) * 8;
        float acc[8];
        #pragma unroll
        for (int i = 0; i < 8; i++) acc[i] = bo[e0 + i];
        const float* rp = rep + (size_t)bn * HF_ * 64 + l;
        for (int c = 0; c < HF_; c++) {
            float rv = rp[(size_t)c * 64];
            #pragma unroll
            for (int i = 0; i < 8; i++) acc[i] += rv * woT[c * 32 + e0 + i];
        }
        #pragma unroll
        for (int i = 0; i < 8; i++) dt[l * 32 + e0 + i] = acc[i];
    }
    __syncthreads();
    const float m = mean_i[bn], sd = std_i[bn];
    for (int p = tid; p < PRED_; p += 256) {
        float acc = hb[p];
        const float* w = hw + (size_t)p * HNF_;
        for (int f = 0; f < DFF_; f++) {
            const float* wf = w + f * 64;
            #pragma unroll
            for (int ll = 0; ll < 64; ll++) acc += dt[ll * 32 + f] * wf[ll];
        }
        out[(size_t)b * PRED_ * N_ + (size_t)p * N_ + n] = acc * sd + m;
    }
}

extern "C" void kernel_launch(void* const* d_in, const int* in_sizes, int n_in,
                              void* d_out, int out_size, void* d_ws, size_t ws_size,
                              hipStream_t stream) {
    const float* x_enc   = (const float*)d_in[0];
    const float* conv_w  = (const float*)d_in[1];
    const float* word_emb= (const float*)d_in[2];
    const float* map_w   = (const float*)d_in[3];
    const float* map_b   = (const float*)d_in[4];
    const float* wq      = (const float*)d_in[5];
    const float* bq      = (const float*)d_in[6];
    const float* wk      = (const float*)d_in[7];
    const float* bk      = (const float*)d_in[8];
    const float* wv      = (const float*)d_in[9];
    const float* bv      = (const float*)d_in[10];
    const float* wo      = (const float*)d_in[11];
    const float* bo      = (const float*)d_in[12];
    const float* head_w  = (const float*)d_in[13];
    const float* head_b  = (const float*)d_in[14];

    float* ws = (float*)d_ws;
    float* mean_w = ws;                          // 256
    float* std_w  = ws + 256;                    // 256
    float* wsum_w = ws + 512;                    // 512
    float* q_w    = ws + 1024;                   // 224*16384
    float* kv_w   = q_w + (size_t)BN_ * L_ * HF_;// 2 MB region for bf16 K/V^T
    float* cp_w   = kv_w + (size_t)S_ * 512;     // 25*1000*512 (51.2 MB)
    float* rep_w  = cp_w;                        // alias: cp dead after k_red
    ushort* et_w  = (ushort*)(cp_w + (size_t)KSPLIT2 * S_ * 512);  // 512*32000 bf16
    ushort* wkv_w = et_w + (size_t)512 * V_;                       // 512*4096 bf16
    ushort* kb_w  = (ushort*)kv_w;               // [1024][256] bf16 (512 KB)
    ushort* vt_w  = kb_w + (size_t)SP_ * HF_;    // [256][1024] bf16 (512 KB)

    k_pre<<<BN_, 256, 0, stream>>>(x_enc, conv_w, wq, bq, mean_w, std_w, q_w);
    k_wsum<<<512, 256, 0, stream>>>(wk, wv, wsum_w);
    k_cvt_wkv<<<(512 * DLLM_ / 8) / 256, 256, 0, stream>>>(wk, wv, wkv_w);
    k_gemm1<<<dim3(2, V_ / 128), 512, 0, stream>>>(word_emb, wkv_w, et_w);
    k_gemm2<<<dim3(8, 4, KSPLIT2), 256, 0, stream>>>(map_w, et_w, cp_w);
    k_red<<<(SP_ * 512) / 256, 256, 0, stream>>>(cp_w, map_b, wsum_w, bk, bv, kb_w, vt_w);
    k_attn<<<dim3(NH_, BN_), 256, 0, stream>>>(q_w, kb_w, vt_w, rep_w);
    k_post<<<BN_, 256, 0, stream>>>(rep_w, wo, bo, head_w, head_b, mean_w, std_w, (float*)d_out);
}